// Round 8
// baseline (95.671 us; speedup 1.0000x reference)
//
#include <hip/hip_runtime.h>
#include <math.h>

#define B   8
#define S   256
#define NT  50
#define E   64
#define NTE (NT * E)
#define EPSF 1e-16f
#define LOG2E 1.4426950408889634f

#define NW        8                 // waves per block (512 threads)
#define NTHREADS  (64 * NW)
#define LL_BLOCKS (B * S / 2)       // 1024 blocks; rows (ih, S-1-ih)
#define IN_BLOCKS (B * NT)          // 400 blocks

__device__ __forceinline__ float softplus(float x) {
    if (x > 20.0f) return x;
    return log1pf(__expf(x));
}

__device__ __forceinline__ float wave_reduce_sum(float v) {
    #pragma unroll
    for (int off = 32; off > 0; off >>= 1)
        v += __shfl_down(v, off, 64);
    return v;  // lane 0 holds the sum
}

// ---------------------------------------------------------------------------
// Main kernel. Grid = LL_BLOCKS + IN_BLOCKS, 512 threads (8 waves).
//
// Type-grouped (CSR) formulation: per block, events of batch b are counting-
// sorted by type into s_evt (time, orig_index). For a row i the sum over
// history factorizes per type ty:
//   m[e] = sum_ty (A[ty][tyi][e]*ej[e]) * sum_{j in ty, j<i} exp(wc*dt_j)
// so A/P/ej are loaded once per (row,type) -- ~50 coalesced loads -- and the
// per-event work is {uniform LDS b64 + mul + exp2 + select-add}. Both rows of
// the pair share one event scan (two independent exp chains). Waves split the
// type dimension. No s_emb staging; LDS ~9 KB.
// ---------------------------------------------------------------------------
__global__ __launch_bounds__(NTHREADS, 8) void main_kernel(
    const float* __restrict__ times, const int* __restrict__ types,
    const int* __restrict__ Tp,
    const float* __restrict__ emb,  const float* __restrict__ a,
    const float* __restrict__ Amat, const float* __restrict__ Pmat,
    float* __restrict__ ws_ll, float* __restrict__ ws_int)
{
    const int tid = threadIdx.x;
    const int e   = tid & 63;
    const int w   = tid >> 6;
    const int bid = blockIdx.x;
    const bool is_ll = (bid < LL_BLOCKS);
    const int b = is_ll ? (bid / (S / 2)) : ((bid - LL_BLOCKS) / NT);

    __shared__ float2 s_evt[S];        // CSR payload: (t_j, bits(j))
    __shared__ float  s_tm[S];
    __shared__ int    s_ty[S];
    __shared__ int    s_cnt[NT];
    __shared__ int    s_beg[NT + 1];   // CSR offsets
    __shared__ int    s_pos[NT];       // scatter cursors
    __shared__ float  s_part[2][NW][E];
    __shared__ float  s_row[2];

    // ---- prologue: stage events, build per-type CSR ----------------------
    if (tid < NT) s_cnt[tid] = 0;
    if (tid < S) {
        s_tm[tid] = times[b * S + tid];
        s_ty[tid] = types[b * S + tid];
    }
    __syncthreads();
    if (tid < S) atomicAdd(&s_cnt[s_ty[tid]], 1);
    __syncthreads();
    if (tid < 64) {                    // wave 0: shuffle inclusive scan
        int v = (tid < NT) ? s_cnt[tid] : 0;
        const int cnt = v;
        #pragma unroll
        for (int off = 1; off < 64; off <<= 1) {
            const int u = __shfl_up(v, off, 64);
            if (tid >= off) v += u;
        }
        if (tid < NT) { s_beg[tid + 1] = v; s_pos[tid] = v - cnt; }
        if (tid == 0) s_beg[0] = 0;
    }
    __syncthreads();
    if (tid < S) {
        const int p = atomicAdd(&s_pos[s_ty[tid]], 1);
        s_evt[p] = make_float2(s_tm[tid], __int_as_float(tid));
    }
    __syncthreads();

    if (is_ll) {
        const int ih = bid % (S / 2);
        const int i0 = ih, i1 = S - 1 - ih;          // i0 < i1
        const float t0 = s_tm[i0], t1 = s_tm[i1];
        const int col0 = s_ty[i0] * E + e;
        const int col1 = s_ty[i1] * E + e;
        const float negE0 = -emb[col0] * LOG2E;
        const float negE1 = -emb[col1] * LOG2E;

        float m0 = 0.0f, m1 = 0.0f;
        for (int ty = w; ty < NT; ty += NW) {
            const int beg = s_beg[ty], end = s_beg[ty + 1];
            if (beg == end) continue;                // uniform skip
            const int   rb = ty * NTE;
            const float ej = emb[ty * E + e];
            const float A0 = Amat[rb + col0], P0 = Pmat[rb + col0];
            const float A1 = Amat[rb + col1], P1 = Pmat[rb + col1];
            const float wc0 = negE0 * P0 * ej;
            const float wc1 = negE1 * P1 * ej;
            float s0 = 0.0f, s1 = 0.0f;
            for (int q = beg; q < end; ++q) {
                const float2 evq = s_evt[q];         // uniform b64 broadcast
                const int    jo  = __float_as_int(evq.y);
                const float  e0  = exp2f(wc0 * (t0 - evq.x));
                const float  e1  = exp2f(wc1 * (t1 - evq.x));
                s0 += (jo < i0) ? e0 : 0.0f;         // select, never inf*0
                s1 += (jo < i1) ? e1 : 0.0f;
            }
            m0 = fmaf(A0 * ej, s0, m0);
            m1 = fmaf(A1 * ej, s1, m1);
        }
        s_part[0][w][e] = m0;
        s_part[1][w][e] = m1;
        __syncthreads();
        if (w < 2) {
            const int   i     = (w == 0) ? i0 : i1;
            const float t_i   = s_tm[i];
            const int   col   = s_ty[i] * E + e;
            const float emb_i = emb[col];
            float mt = 0.0f;
            #pragma unroll
            for (int q = 0; q < NW; ++q) mt += s_part[w][q][e];
            const float sp    = softplus(fmaf(emb_i, mt, emb_i * a[col]));
            const float inten = wave_reduce_sum(sp);
            if (e == 0)
                s_row[w] = (t_i >= 0.0f) ? logf(inten + EPSF) : 0.0f;
        }
        __syncthreads();
        if (tid == 0) ws_ll[bid] = s_row[0] + s_row[1];
    } else {
        const int   k      = (bid - LL_BLOCKS) % NT;
        const float Tf     = (float)(*Tp);
        const int   colk   = k * E + e;
        const float embk   = emb[colk];
        const float negEk2 = -embk * LOG2E;

        float acc = 0.0f;
        for (int ty = w; ty < NT; ty += NW) {
            const int beg = s_beg[ty], end = s_beg[ty + 1];
            if (beg == end) continue;
            const int   rb = ty * NTE;
            const float et = emb[ty * E + e];
            const float Ae = Amat[rb + colk], Pe = Pmat[rb + colk];
            const float u  = negEk2 * Pe * et;
            const float v  = Ae * et;
            float asum = 0.0f;
            for (int q = beg; q < end; ++q) {
                const float2 evq = s_evt[q];
                const float  ex  = exp2f(u * (Tf - evq.x));
                asum += (evq.x >= 0.0f) ? ex : 0.0f;
            }
            acc = fmaf(v, asum, acc);
        }
        s_part[0][w][e] = acc;
        __syncthreads();
        if (w == 0) {
            float mt = 0.0f;
            #pragma unroll
            for (int q = 0; q < NW; ++q) mt += s_part[0][q][e];
            const float sp = softplus(fmaf(embk, mt, embk * a[colk]));
            const float s  = wave_reduce_sum(sp);
            if (e == 0) ws_int[bid - LL_BLOCKS] = s;
        }
    }
}

// ---------------------------------------------------------------------------
// Finalize: one block, 4 waves (verified version, unchanged).
// ---------------------------------------------------------------------------
__global__ __launch_bounds__(256) void finalize_kernel(
    const float* __restrict__ times,
    const int* __restrict__ Tp,
    const float* __restrict__ emb, const float* __restrict__ a,
    const float* __restrict__ ws_ll, const float* __restrict__ ws_int,
    float* __restrict__ out)
{
    const int t    = threadIdx.x;
    const int lane = t & 63;
    const int w    = t >> 6;
    const float Tf = (float)(*Tp);

    float llp = 0.0f;
    for (int idx = t; idx < LL_BLOCKS; idx += 256) llp += ws_ll[idx];
    float bs = 0.0f;
    for (int idx = t; idx < NTE; idx += 256) bs += softplus(emb[idx] * a[idx]);

    __shared__ float red[256], red2[256];
    red[t] = llp; red2[t] = bs;

    __shared__ float s_first[B], s_last[B], s_iT[B], s_any[B];
    for (int b = w; b < B; b += 4) {
        float mn = 1e30f, mx = -1e30f;
        #pragma unroll
        for (int q = 0; q < S / 64; ++q) {
            const float tv = times[b * S + q * 64 + lane];
            const bool valid = (tv >= 0.0f);
            mn = fminf(mn, valid ? tv : 1e30f);
            mx = fmaxf(mx, valid ? tv : -1e30f);
        }
        float iv = (lane < NT) ? ws_int[b * NT + lane] : 0.0f;
        #pragma unroll
        for (int off = 32; off > 0; off >>= 1) {
            mn = fminf(mn, __shfl_down(mn, off, 64));
            mx = fmaxf(mx, __shfl_down(mx, off, 64));
            iv += __shfl_down(iv, off, 64);
        }
        if (lane == 0) {
            const bool any_valid = (mn < 1e29f);
            s_any[b]   = any_valid ? 1.0f : 0.0f;
            s_first[b] = any_valid ? mn : 0.0f;
            s_last[b]  = any_valid ? mx : 0.0f;
            s_iT[b]    = iv;
        }
    }
    __syncthreads();

    for (int off = 128; off > 0; off >>= 1) {
        if (t < off) { red[t] += red[t + off]; red2[t] += red2[t + off]; }
        __syncthreads();
    }

    if (t == 0) {
        const float base_sum = red2[0];
        float integral = 0.0f;
        #pragma unroll
        for (int b = 0; b < B; ++b) {
            integral += (s_any[b] > 0.5f)
                ? s_iT[b] * (Tf - s_last[b]) + base_sum * s_first[b]
                : base_sum * Tf;
        }
        out[0] = integral - red[0];
    }
}

extern "C" void kernel_launch(void* const* d_in, const int* in_sizes, int n_in,
                              void* d_out, int out_size, void* d_ws, size_t ws_size,
                              hipStream_t stream) {
    const float* times = (const float*)d_in[0];
    const int*   types = (const int*)d_in[1];
    const int*   Tp    = (const int*)d_in[2];
    const float* emb   = (const float*)d_in[3];
    const float* a     = (const float*)d_in[4];
    const float* Amat  = (const float*)d_in[5];
    const float* Pmat  = (const float*)d_in[6];

    float* ws     = (float*)d_ws;
    float* ws_ll  = ws;                  // [0, 1024)
    float* ws_int = ws + LL_BLOCKS;      // [1024, 1424)
    float* out    = (float*)d_out;

    main_kernel<<<LL_BLOCKS + IN_BLOCKS, NTHREADS, 0, stream>>>(
        times, types, Tp, emb, a, Amat, Pmat, ws_ll, ws_int);
    finalize_kernel<<<1, 256, 0, stream>>>(times, Tp, emb, a, ws_ll, ws_int, out);
}

// Round 9
// 93.784 us; speedup vs baseline: 1.0201x; 1.0201x over previous
//
#include <hip/hip_runtime.h>
#include <math.h>

#define B   8
#define S   256
#define NT  50
#define E   64
#define NTE (NT * E)
#define EPSF 1e-16f
#define LOG2E 1.4426950408889634f

#define NW        8                 // waves per block (512 threads)
#define NTHREADS  (64 * NW)
#define LL_BLOCKS (B * S / 2)       // 1024 blocks; rows (ih, S-1-ih)
#define IN_BLOCKS (B * NT)          // 400 blocks

__device__ __forceinline__ float softplus(float x) {
    if (x > 20.0f) return x;
    return log1pf(__expf(x));
}

__device__ __forceinline__ float wave_reduce_sum(float v) {
    #pragma unroll
    for (int off = 32; off > 0; off >>= 1)
        v += __shfl_down(v, off, 64);
    return v;  // lane 0 holds the sum
}

// ---------------------------------------------------------------------------
// Main kernel. Grid = LL_BLOCKS + IN_BLOCKS, 512 threads (8 waves).
//
// STABLE type-grouped CSR: events are counting-sorted by (type, original
// index) -- original index order == time order (times sorted). Stability via
// per-type 256-bit LDS bitmask + popcount rank (no atomic-order dependence).
// Within a type events are j-ascending, so for the row pair (i0 < i1) the
// scan visits only the prefix jo < i1 (uniform break): row-1 exp always,
// row-0 exp only while jo < i0. Exp count per block = i0+i1 = 255 (parity
// with the direct kernel) but the event loop has ZERO gathered loads:
// A/P/ej are loaded once per (row,type) -- ~250 coalesced gathers/block vs
// ~1020 -- and per-event work is {uniform LDS b64 + ~4 VALU + exp2}.
// Waves split the type dimension. LDS ~10 KB.
// ---------------------------------------------------------------------------
__global__ __launch_bounds__(NTHREADS, 8) void main_kernel(
    const float* __restrict__ times, const int* __restrict__ types,
    const int* __restrict__ Tp,
    const float* __restrict__ emb,  const float* __restrict__ a,
    const float* __restrict__ Amat, const float* __restrict__ Pmat,
    float* __restrict__ ws_ll, float* __restrict__ ws_int)
{
    const int tid = threadIdx.x;
    const int e   = tid & 63;
    const int w   = tid >> 6;
    const int bid = blockIdx.x;
    const bool is_ll = (bid < LL_BLOCKS);
    const int b = is_ll ? (bid / (S / 2)) : ((bid - LL_BLOCKS) / NT);

    __shared__ float  s_tm[S];                       // 1 KB
    __shared__ int    s_ty[S];                       // 1 KB
    __shared__ unsigned long long s_mask[NT][4];     // 1.6 KB type bitmasks
    __shared__ int    s_beg[NT + 1];                 // CSR offsets
    __shared__ float2 s_evt[S];                      // 2 KB (t_j, bits(j))
    __shared__ float  s_part[2][NW][E];              // 4 KB
    __shared__ float  s_row[2];

    // ---- prologue: stage events, stable counting sort by type ------------
    if (tid < NT * 4) ((unsigned long long*)s_mask)[tid] = 0ull;
    if (tid < S) {
        s_tm[tid] = times[b * S + tid];
        s_ty[tid] = types[b * S + tid];
    }
    __syncthreads();
    if (tid < S)
        atomicOr(&s_mask[s_ty[tid]][tid >> 6], 1ull << (tid & 63));
    __syncthreads();
    if (tid < 64) {                    // wave 0: counts + inclusive scan
        int cnt = 0;
        if (tid < NT) {
            #pragma unroll
            for (int q = 0; q < 4; ++q) cnt += __popcll(s_mask[tid][q]);
        }
        int v = cnt;
        #pragma unroll
        for (int off = 1; off < 64; off <<= 1) {
            const int u = __shfl_up(v, off, 64);
            if (tid >= off) v += u;
        }
        if (tid < NT) s_beg[tid + 1] = v;
        if (tid == 0) s_beg[0] = 0;
    }
    __syncthreads();
    if (tid < S) {
        const int ty = s_ty[tid];
        const int jw = tid >> 6, jb = tid & 63;
        int rank = __popcll(s_mask[ty][jw] & ((1ull << jb) - 1ull));
        for (int q = 0; q < jw; ++q) rank += __popcll(s_mask[ty][q]);
        s_evt[s_beg[ty] + rank] = make_float2(s_tm[tid], __int_as_float(tid));
    }
    __syncthreads();

    if (is_ll) {
        const int ih = bid % (S / 2);
        const int i0 = ih, i1 = S - 1 - ih;          // i0 < i1
        const float t0 = s_tm[i0], t1 = s_tm[i1];
        const int col0 = s_ty[i0] * E + e;
        const int col1 = s_ty[i1] * E + e;
        const float negE0 = -emb[col0] * LOG2E;
        const float negE1 = -emb[col1] * LOG2E;

        float m0 = 0.0f, m1 = 0.0f;
        for (int ty = w; ty < NT; ty += NW) {
            const int beg = s_beg[ty], end = s_beg[ty + 1];
            if (beg == end) continue;                // uniform skip
            // first event of this type must be < i1 to matter at all
            if (__float_as_int(s_evt[beg].y) >= i1) continue;
            const int   rb = ty * NTE;
            const float ej = emb[ty * E + e];
            const float A0 = Amat[rb + col0], P0 = Pmat[rb + col0];
            const float A1 = Amat[rb + col1], P1 = Pmat[rb + col1];
            const float wc0 = negE0 * P0 * ej;
            const float wc1 = negE1 * P1 * ej;
            float s0 = 0.0f, s1 = 0.0f;
            for (int q = beg; q < end; ++q) {
                const float2 evq = s_evt[q];         // uniform b64 broadcast
                const int    jo  = __float_as_int(evq.y);
                if (jo >= i1) break;                 // uniform (j-ascending)
                s1 += exp2f(wc1 * (t1 - evq.x));
                if (jo < i0)                         // uniform
                    s0 += exp2f(wc0 * (t0 - evq.x));
            }
            m0 = fmaf(A0 * ej, s0, m0);
            m1 = fmaf(A1 * ej, s1, m1);
        }
        s_part[0][w][e] = m0;
        s_part[1][w][e] = m1;
        __syncthreads();
        if (w < 2) {
            const int   i     = (w == 0) ? i0 : i1;
            const float t_i   = s_tm[i];
            const int   col   = s_ty[i] * E + e;
            const float emb_i = emb[col];
            float mt = 0.0f;
            #pragma unroll
            for (int q = 0; q < NW; ++q) mt += s_part[w][q][e];
            const float sp    = softplus(fmaf(emb_i, mt, emb_i * a[col]));
            const float inten = wave_reduce_sum(sp);
            if (e == 0)
                s_row[w] = (t_i >= 0.0f) ? logf(inten + EPSF) : 0.0f;
        }
        __syncthreads();
        if (tid == 0) ws_ll[bid] = s_row[0] + s_row[1];
    } else {
        const int   k      = (bid - LL_BLOCKS) % NT;
        const float Tf     = (float)(*Tp);
        const int   colk   = k * E + e;
        const float embk   = emb[colk];
        const float negEk2 = -embk * LOG2E;

        float acc = 0.0f;
        for (int ty = w; ty < NT; ty += NW) {
            const int beg = s_beg[ty], end = s_beg[ty + 1];
            if (beg == end) continue;
            const int   rb = ty * NTE;
            const float et = emb[ty * E + e];
            const float Ae = Amat[rb + colk], Pe = Pmat[rb + colk];
            const float u  = negEk2 * Pe * et;
            const float v  = Ae * et;
            float asum = 0.0f;
            #pragma unroll 4
            for (int q = beg; q < end; ++q) {
                const float2 evq = s_evt[q];
                const float  ex  = exp2f(u * (Tf - evq.x));
                asum += (evq.x >= 0.0f) ? ex : 0.0f;
            }
            acc = fmaf(v, asum, acc);
        }
        s_part[0][w][e] = acc;
        __syncthreads();
        if (w == 0) {
            float mt = 0.0f;
            #pragma unroll
            for (int q = 0; q < NW; ++q) mt += s_part[0][q][e];
            const float sp = softplus(fmaf(embk, mt, embk * a[colk]));
            const float s  = wave_reduce_sum(sp);
            if (e == 0) ws_int[bid - LL_BLOCKS] = s;
        }
    }
}

// ---------------------------------------------------------------------------
// Finalize: one block, 4 waves (verified version, unchanged).
// ---------------------------------------------------------------------------
__global__ __launch_bounds__(256) void finalize_kernel(
    const float* __restrict__ times,
    const int* __restrict__ Tp,
    const float* __restrict__ emb, const float* __restrict__ a,
    const float* __restrict__ ws_ll, const float* __restrict__ ws_int,
    float* __restrict__ out)
{
    const int t    = threadIdx.x;
    const int lane = t & 63;
    const int w    = t >> 6;
    const float Tf = (float)(*Tp);

    float llp = 0.0f;
    for (int idx = t; idx < LL_BLOCKS; idx += 256) llp += ws_ll[idx];
    float bs = 0.0f;
    for (int idx = t; idx < NTE; idx += 256) bs += softplus(emb[idx] * a[idx]);

    __shared__ float red[256], red2[256];
    red[t] = llp; red2[t] = bs;

    __shared__ float s_first[B], s_last[B], s_iT[B], s_any[B];
    for (int b = w; b < B; b += 4) {
        float mn = 1e30f, mx = -1e30f;
        #pragma unroll
        for (int q = 0; q < S / 64; ++q) {
            const float tv = times[b * S + q * 64 + lane];
            const bool valid = (tv >= 0.0f);
            mn = fminf(mn, valid ? tv : 1e30f);
            mx = fmaxf(mx, valid ? tv : -1e30f);
        }
        float iv = (lane < NT) ? ws_int[b * NT + lane] : 0.0f;
        #pragma unroll
        for (int off = 32; off > 0; off >>= 1) {
            mn = fminf(mn, __shfl_down(mn, off, 64));
            mx = fmaxf(mx, __shfl_down(mx, off, 64));
            iv += __shfl_down(iv, off, 64);
        }
        if (lane == 0) {
            const bool any_valid = (mn < 1e29f);
            s_any[b]   = any_valid ? 1.0f : 0.0f;
            s_first[b] = any_valid ? mn : 0.0f;
            s_last[b]  = any_valid ? mx : 0.0f;
            s_iT[b]    = iv;
        }
    }
    __syncthreads();

    for (int off = 128; off > 0; off >>= 1) {
        if (t < off) { red[t] += red[t + off]; red2[t] += red2[t + off]; }
        __syncthreads();
    }

    if (t == 0) {
        const float base_sum = red2[0];
        float integral = 0.0f;
        #pragma unroll
        for (int b = 0; b < B; ++b) {
            integral += (s_any[b] > 0.5f)
                ? s_iT[b] * (Tf - s_last[b]) + base_sum * s_first[b]
                : base_sum * Tf;
        }
        out[0] = integral - red[0];
    }
}

extern "C" void kernel_launch(void* const* d_in, const int* in_sizes, int n_in,
                              void* d_out, int out_size, void* d_ws, size_t ws_size,
                              hipStream_t stream) {
    const float* times = (const float*)d_in[0];
    const int*   types = (const int*)d_in[1];
    const int*   Tp    = (const int*)d_in[2];
    const float* emb   = (const float*)d_in[3];
    const float* a     = (const float*)d_in[4];
    const float* Amat  = (const float*)d_in[5];
    const float* Pmat  = (const float*)d_in[6];

    float* ws     = (float*)d_ws;
    float* ws_ll  = ws;                  // [0, 1024)
    float* ws_int = ws + LL_BLOCKS;      // [1024, 1424)
    float* out    = (float*)d_out;

    main_kernel<<<LL_BLOCKS + IN_BLOCKS, NTHREADS, 0, stream>>>(
        times, types, Tp, emb, a, Amat, Pmat, ws_ll, ws_int);
    finalize_kernel<<<1, 256, 0, stream>>>(times, Tp, emb, a, ws_ll, ws_int, out);
}

// Round 10
// 89.078 us; speedup vs baseline: 1.0740x; 1.0528x over previous
//
#include <hip/hip_runtime.h>
#include <math.h>

#define B   8
#define S   256
#define NT  50
#define E   64
#define NTE (NT * E)
#define EPSF 1e-16f

#define NW        8                 // waves per block (512 threads)
#define NTHREADS  (64 * NW)
#define LL_BLOCKS (B * S / 2)       // 1024 blocks; each handles rows (ih, S-1-ih)
#define IN_BLOCKS (B * NT)          // 400 blocks

__device__ __forceinline__ float softplus(float x) {
    if (x > 20.0f) return x;
    return log1pf(__expf(x));
}

__device__ __forceinline__ float wave_reduce_sum(float v) {
    #pragma unroll
    for (int off = 32; off > 0; off >>= 1)
        v += __shfl_down(v, off, 64);
    return v;  // lane 0 holds the sum
}

// ---------------------------------------------------------------------------
// Main kernel. Grid = LL_BLOCKS + IN_BLOCKS, 512 threads (8 waves).
//
// BYTE-IDENTICAL to the best verified kernel (r7, 87.3us) except ONE change:
// __launch_bounds__ min-waves 8 -> 4, lifting the VGPR cap from 64 to 128.
// At 64 the allocator (observed VGPR_Count=40) could keep only ~2 of the 8
// unrolled iterations' {ev, ej, A, P} values in flight, so each wave's ~32
// inner iterations ran as a near-serial 250-500cy latency chain -- the
// invariant ~37us main across all structural variants. With 128 VGPRs the
// unroll-8 pipeline (~90 regs) fits: 8 iterations' LDS+global loads issue
// back-to-back before the first exp consumes them.
// Occupancy halves (2 blocks/CU) but outstanding loads per SIMD double.
// ---------------------------------------------------------------------------
__global__ __launch_bounds__(NTHREADS, 4) void main_kernel(
    const float* __restrict__ times, const int* __restrict__ types,
    const int* __restrict__ Tp,
    const float* __restrict__ emb,  const float* __restrict__ a,
    const float* __restrict__ Amat, const float* __restrict__ Pmat,
    float* __restrict__ ws_ll, float* __restrict__ ws_int)
{
    const int tid = threadIdx.x;
    const int e   = tid & 63;
    const int w   = tid >> 6;
    const int bid = blockIdx.x;
    const bool is_ll = (bid < LL_BLOCKS);
    const int b = is_ll ? (bid / (S / 2)) : ((bid - LL_BLOCKS) / NT);

    __shared__ __align__(16) float  s_emb[NTE];   // 12.8 KB, lane-contiguous
    __shared__ __align__(16) float4 s_ev[S];      // (t, ty*E, ty*NTE, 0) bits
    __shared__ float s_part[2][NW][E];            // 4 KB
    __shared__ float s_row[2];

    {
        const float4* __restrict__ emb4 = (const float4*)emb;
        float4* s4 = (float4*)s_emb;
        for (int idx = tid; idx < NTE / 4; idx += NTHREADS)
            s4[idx] = emb4[idx];
    }
    for (int j = tid; j < S; j += NTHREADS) {
        const int ty = types[b * S + j];
        s_ev[j] = make_float4(times[b * S + j],
                              __int_as_float(ty * E),
                              __int_as_float(ty * NTE), 0.0f);
    }
    __syncthreads();

    if (is_ll) {
        const int ih = bid % (S / 2);
        const int rows[2] = { ih, S - 1 - ih };
        #pragma unroll
        for (int r = 0; r < 2; ++r) {
            const int   i     = rows[r];
            const float t_i   = s_ev[i].x;
            const int   col   = __float_as_int(s_ev[i].y) + e;   // tyi*E + e
            const float negEi = -s_emb[col];

            float macc = 0.0f;
            #pragma unroll 8
            for (int j = w; j < i; j += NW) {
                const float4 ev  = s_ev[j];                      // uniform b128
                const float  dtj = t_i - ev.x;
                const int   base = __float_as_int(ev.z) + col;   // tyj*NTE+col
                const float ej   = s_emb[__float_as_int(ev.y) + e];
                const float Pe   = Pmat[base];
                const float Ae   = Amat[base];
                macc = fmaf(Ae * ej, __expf(negEi * Pe * ej * dtj), macc);
            }
            s_part[r][w][e] = macc;
        }
        __syncthreads();
        if (w < 2) {
            const int   i     = rows[w];
            const float t_i   = s_ev[i].x;
            const int   col   = __float_as_int(s_ev[i].y) + e;
            const float emb_i = s_emb[col];
            float mt = 0.0f;
            #pragma unroll
            for (int q = 0; q < NW; ++q) mt += s_part[w][q][e];
            const float sp    = softplus(fmaf(emb_i, mt, emb_i * a[col]));
            const float inten = wave_reduce_sum(sp);
            if (e == 0)
                s_row[w] = (t_i >= 0.0f) ? logf(inten + EPSF) : 0.0f;
        }
        __syncthreads();
        if (tid == 0) ws_ll[bid] = s_row[0] + s_row[1];
    } else {
        const int   k     = (bid - LL_BLOCKS) % NT;
        const float Tf    = (float)(*Tp);
        const int   colk  = k * E + e;
        const float embk  = s_emb[colk];
        const float negEk = -embk;

        float acc = 0.0f;
        #pragma unroll 8
        for (int i = w; i < S; i += NW) {
            const float4 ev  = s_ev[i];
            const float  dT  = Tf - ev.x;
            const int   base = __float_as_int(ev.z) + colk;
            const float et   = s_emb[__float_as_int(ev.y) + e];
            const float c    = Amat[base] * et * __expf(negEk * Pmat[base] * et * dT);
            acc += (ev.x >= 0.0f) ? c : 0.0f;   // predicated, no branch
        }
        s_part[0][w][e] = acc;
        __syncthreads();
        if (w == 0) {
            float mt = 0.0f;
            #pragma unroll
            for (int q = 0; q < NW; ++q) mt += s_part[0][q][e];
            const float sp = softplus(fmaf(embk, mt, embk * a[colk]));
            const float s  = wave_reduce_sum(sp);
            if (e == 0) ws_int[bid - LL_BLOCKS] = s;
        }
    }
}

// ---------------------------------------------------------------------------
// Finalize: one block, 4 waves (verified version, unchanged).
// ---------------------------------------------------------------------------
__global__ __launch_bounds__(256) void finalize_kernel(
    const float* __restrict__ times,
    const int* __restrict__ Tp,
    const float* __restrict__ emb, const float* __restrict__ a,
    const float* __restrict__ ws_ll, const float* __restrict__ ws_int,
    float* __restrict__ out)
{
    const int t    = threadIdx.x;
    const int lane = t & 63;
    const int w    = t >> 6;
    const float Tf = (float)(*Tp);

    float llp = 0.0f;
    for (int idx = t; idx < LL_BLOCKS; idx += 256) llp += ws_ll[idx];
    float bs = 0.0f;
    for (int idx = t; idx < NTE; idx += 256) bs += softplus(emb[idx] * a[idx]);

    __shared__ float red[256], red2[256];
    red[t] = llp; red2[t] = bs;

    __shared__ float s_first[B], s_last[B], s_iT[B], s_any[B];
    for (int b = w; b < B; b += 4) {
        float mn = 1e30f, mx = -1e30f;
        #pragma unroll
        for (int q = 0; q < S / 64; ++q) {
            const float tv = times[b * S + q * 64 + lane];
            const bool valid = (tv >= 0.0f);
            mn = fminf(mn, valid ? tv : 1e30f);
            mx = fmaxf(mx, valid ? tv : -1e30f);
        }
        float iv = (lane < NT) ? ws_int[b * NT + lane] : 0.0f;
        #pragma unroll
        for (int off = 32; off > 0; off >>= 1) {
            mn = fminf(mn, __shfl_down(mn, off, 64));
            mx = fmaxf(mx, __shfl_down(mx, off, 64));
            iv += __shfl_down(iv, off, 64);
        }
        if (lane == 0) {
            const bool any_valid = (mn < 1e29f);
            s_any[b]   = any_valid ? 1.0f : 0.0f;
            s_first[b] = any_valid ? mn : 0.0f;
            s_last[b]  = any_valid ? mx : 0.0f;
            s_iT[b]    = iv;
        }
    }
    __syncthreads();

    for (int off = 128; off > 0; off >>= 1) {
        if (t < off) { red[t] += red[t + off]; red2[t] += red2[t + off]; }
        __syncthreads();
    }

    if (t == 0) {
        const float base_sum = red2[0];
        float integral = 0.0f;
        #pragma unroll
        for (int b = 0; b < B; ++b) {
            integral += (s_any[b] > 0.5f)
                ? s_iT[b] * (Tf - s_last[b]) + base_sum * s_first[b]
                : base_sum * Tf;
        }
        out[0] = integral - red[0];
    }
}

extern "C" void kernel_launch(void* const* d_in, const int* in_sizes, int n_in,
                              void* d_out, int out_size, void* d_ws, size_t ws_size,
                              hipStream_t stream) {
    const float* times = (const float*)d_in[0];
    const int*   types = (const int*)d_in[1];
    const int*   Tp    = (const int*)d_in[2];
    const float* emb   = (const float*)d_in[3];
    const float* a     = (const float*)d_in[4];
    const float* Amat  = (const float*)d_in[5];
    const float* Pmat  = (const float*)d_in[6];

    float* ws     = (float*)d_ws;
    float* ws_ll  = ws;                  // [0, 1024)
    float* ws_int = ws + LL_BLOCKS;      // [1024, 1424)
    float* out    = (float*)d_out;

    main_kernel<<<LL_BLOCKS + IN_BLOCKS, NTHREADS, 0, stream>>>(
        times, types, Tp, emb, a, Amat, Pmat, ws_ll, ws_int);
    finalize_kernel<<<1, 256, 0, stream>>>(times, Tp, emb, a, ws_ll, ws_int, out);
}

// Round 11
// 88.244 us; speedup vs baseline: 1.0842x; 1.0095x over previous
//
#include <hip/hip_runtime.h>
#include <math.h>

#define B   8
#define S   256
#define NT  50
#define E   64
#define NTE (NT * E)
#define EPSF 1e-16f

#define NW        8                 // waves per block (512 threads)
#define NTHREADS  (64 * NW)
#define LL_BLOCKS (B * S / 2)       // 1024 blocks; each handles rows (ih, S-1-ih)
#define IN_BLOCKS (B * NT)          // 400 logical (b,k) tiles, folded into blocks 0..399

__device__ __forceinline__ float softplus(float x) {
    if (x > 20.0f) return x;
    return log1pf(__expf(x));
}

__device__ __forceinline__ float wave_reduce_sum(float v) {
    #pragma unroll
    for (int off = 32; off > 0; off >>= 1)
        v += __shfl_down(v, off, 64);
    return v;  // lane 0 holds the sum
}

// ---------------------------------------------------------------------------
// Main kernel. Grid = 1024 blocks, 512 threads (8 waves).
//
// Body identical to the best-measured kernel (r7, 87.3us). ONE structural
// change: the 400 integral (b,k) tiles are FOLDED into blocks 0..399 instead
// of being 400 separate blocks. After the LL epilogue barrier, those blocks
// restage s_ev for the integral batch (s_emb is batch-independent and already
// in LDS) and run the 32-iteration integral loop. This removes 400 block
// prologues (each staged 12.8 KB of emb = ~5.1 MB of the 5.2 MB FETCH_SIZE),
// 400 scheduling slots, and makes the grid exactly 4 blocks/CU uniform.
// ---------------------------------------------------------------------------
__global__ __launch_bounds__(NTHREADS, 8) void main_kernel(
    const float* __restrict__ times, const int* __restrict__ types,
    const int* __restrict__ Tp,
    const float* __restrict__ emb,  const float* __restrict__ a,
    const float* __restrict__ Amat, const float* __restrict__ Pmat,
    float* __restrict__ ws_ll, float* __restrict__ ws_int)
{
    const int tid = threadIdx.x;
    const int e   = tid & 63;
    const int w   = tid >> 6;
    const int bid = blockIdx.x;
    const int b   = bid / (S / 2);              // LL batch

    __shared__ __align__(16) float  s_emb[NTE];   // 12.8 KB, lane-contiguous
    __shared__ __align__(16) float4 s_ev[S];      // (t, ty*E, ty*NTE, 0) bits
    __shared__ float s_part[2][NW][E];            // 4 KB
    __shared__ float s_row[2];

    {
        const float4* __restrict__ emb4 = (const float4*)emb;
        float4* s4 = (float4*)s_emb;
        for (int idx = tid; idx < NTE / 4; idx += NTHREADS)
            s4[idx] = emb4[idx];
    }
    for (int j = tid; j < S; j += NTHREADS) {
        const int ty = types[b * S + j];
        s_ev[j] = make_float4(times[b * S + j],
                              __int_as_float(ty * E),
                              __int_as_float(ty * NTE), 0.0f);
    }
    __syncthreads();

    // ---- LL row pair (identical to r7) -----------------------------------
    {
        const int ih = bid % (S / 2);
        const int rows[2] = { ih, S - 1 - ih };
        #pragma unroll
        for (int r = 0; r < 2; ++r) {
            const int   i     = rows[r];
            const float t_i   = s_ev[i].x;
            const int   col   = __float_as_int(s_ev[i].y) + e;   // tyi*E + e
            const float negEi = -s_emb[col];

            float macc = 0.0f;
            #pragma unroll 8
            for (int j = w; j < i; j += NW) {
                const float4 ev  = s_ev[j];                      // uniform b128
                const float  dtj = t_i - ev.x;
                const int   base = __float_as_int(ev.z) + col;   // tyj*NTE+col
                const float ej   = s_emb[__float_as_int(ev.y) + e];
                const float Pe   = Pmat[base];
                const float Ae   = Amat[base];
                macc = fmaf(Ae * ej, __expf(negEi * Pe * ej * dtj), macc);
            }
            s_part[r][w][e] = macc;
        }
        __syncthreads();
        if (w < 2) {
            const int   i     = rows[w];
            const float t_i   = s_ev[i].x;
            const int   col   = __float_as_int(s_ev[i].y) + e;
            const float emb_i = s_emb[col];
            float mt = 0.0f;
            #pragma unroll
            for (int q = 0; q < NW; ++q) mt += s_part[w][q][e];
            const float sp    = softplus(fmaf(emb_i, mt, emb_i * a[col]));
            const float inten = wave_reduce_sum(sp);
            if (e == 0)
                s_row[w] = (t_i >= 0.0f) ? logf(inten + EPSF) : 0.0f;
        }
        __syncthreads();                         // also: all s_ev reads done
        if (tid == 0) ws_ll[bid] = s_row[0] + s_row[1];
    }

    // ---- folded integral tile (blocks 0..399) ----------------------------
    if (bid < IN_BLOCKS) {
        const int b2 = bid / NT;                 // integral batch
        const int k  = bid % NT;

        // restage events for batch b2 (s_emb stays valid: batch-independent)
        for (int j = tid; j < S; j += NTHREADS) {
            const int ty = types[b2 * S + j];
            s_ev[j] = make_float4(times[b2 * S + j],
                                  __int_as_float(ty * E),
                                  __int_as_float(ty * NTE), 0.0f);
        }
        __syncthreads();

        const float Tf    = (float)(*Tp);
        const int   colk  = k * E + e;
        const float embk  = s_emb[colk];
        const float negEk = -embk;

        float acc = 0.0f;
        #pragma unroll 8
        for (int i = w; i < S; i += NW) {
            const float4 ev  = s_ev[i];
            const float  dT  = Tf - ev.x;
            const int   base = __float_as_int(ev.z) + colk;
            const float et   = s_emb[__float_as_int(ev.y) + e];
            const float c    = Amat[base] * et * __expf(negEk * Pmat[base] * et * dT);
            acc += (ev.x >= 0.0f) ? c : 0.0f;    // predicated, no branch
        }
        s_part[0][w][e] = acc;
        __syncthreads();
        if (w == 0) {
            float mt = 0.0f;
            #pragma unroll
            for (int q = 0; q < NW; ++q) mt += s_part[0][q][e];
            const float sp = softplus(fmaf(embk, mt, embk * a[colk]));
            const float s  = wave_reduce_sum(sp);
            if (e == 0) ws_int[bid] = s;         // bid == b2*NT + k
        }
    }
}

// ---------------------------------------------------------------------------
// Finalize: one block, 4 waves (verified version, unchanged).
// ---------------------------------------------------------------------------
__global__ __launch_bounds__(256) void finalize_kernel(
    const float* __restrict__ times,
    const int* __restrict__ Tp,
    const float* __restrict__ emb, const float* __restrict__ a,
    const float* __restrict__ ws_ll, const float* __restrict__ ws_int,
    float* __restrict__ out)
{
    const int t    = threadIdx.x;
    const int lane = t & 63;
    const int w    = t >> 6;
    const float Tf = (float)(*Tp);

    float llp = 0.0f;
    for (int idx = t; idx < LL_BLOCKS; idx += 256) llp += ws_ll[idx];
    float bs = 0.0f;
    for (int idx = t; idx < NTE; idx += 256) bs += softplus(emb[idx] * a[idx]);

    __shared__ float red[256], red2[256];
    red[t] = llp; red2[t] = bs;

    __shared__ float s_first[B], s_last[B], s_iT[B], s_any[B];
    for (int b = w; b < B; b += 4) {
        float mn = 1e30f, mx = -1e30f;
        #pragma unroll
        for (int q = 0; q < S / 64; ++q) {
            const float tv = times[b * S + q * 64 + lane];
            const bool valid = (tv >= 0.0f);
            mn = fminf(mn, valid ? tv : 1e30f);
            mx = fmaxf(mx, valid ? tv : -1e30f);
        }
        float iv = (lane < NT) ? ws_int[b * NT + lane] : 0.0f;
        #pragma unroll
        for (int off = 32; off > 0; off >>= 1) {
            mn = fminf(mn, __shfl_down(mn, off, 64));
            mx = fmaxf(mx, __shfl_down(mx, off, 64));
            iv += __shfl_down(iv, off, 64);
        }
        if (lane == 0) {
            const bool any_valid = (mn < 1e29f);
            s_any[b]   = any_valid ? 1.0f : 0.0f;
            s_first[b] = any_valid ? mn : 0.0f;
            s_last[b]  = any_valid ? mx : 0.0f;
            s_iT[b]    = iv;
        }
    }
    __syncthreads();

    for (int off = 128; off > 0; off >>= 1) {
        if (t < off) { red[t] += red[t + off]; red2[t] += red2[t + off]; }
        __syncthreads();
    }

    if (t == 0) {
        const float base_sum = red2[0];
        float integral = 0.0f;
        #pragma unroll
        for (int b = 0; b < B; ++b) {
            integral += (s_any[b] > 0.5f)
                ? s_iT[b] * (Tf - s_last[b]) + base_sum * s_first[b]
                : base_sum * Tf;
        }
        out[0] = integral - red[0];
    }
}

extern "C" void kernel_launch(void* const* d_in, const int* in_sizes, int n_in,
                              void* d_out, int out_size, void* d_ws, size_t ws_size,
                              hipStream_t stream) {
    const float* times = (const float*)d_in[0];
    const int*   types = (const int*)d_in[1];
    const int*   Tp    = (const int*)d_in[2];
    const float* emb   = (const float*)d_in[3];
    const float* a     = (const float*)d_in[4];
    const float* Amat  = (const float*)d_in[5];
    const float* Pmat  = (const float*)d_in[6];

    float* ws     = (float*)d_ws;
    float* ws_ll  = ws;                  // [0, 1024)
    float* ws_int = ws + LL_BLOCKS;      // [1024, 1424)
    float* out    = (float*)d_out;

    main_kernel<<<LL_BLOCKS, NTHREADS, 0, stream>>>(
        times, types, Tp, emb, a, Amat, Pmat, ws_ll, ws_int);
    finalize_kernel<<<1, 256, 0, stream>>>(times, Tp, emb, a, ws_ll, ws_int, out);
}